// Round 6
// baseline (458.959 us; speedup 1.0000x reference)
//
#include <hip/hip_runtime.h>
#include <math.h>

#define B_ 16
#define T_ 2048
#define H_ 512
#define K_ 15
#define M_ (B_*T_)   // 32768

typedef __attribute__((ext_vector_type(8))) short short8;
typedef __attribute__((ext_vector_type(8))) unsigned short ushort8;
typedef __attribute__((ext_vector_type(4))) float f32x4;

__device__ __forceinline__ unsigned short f2bf(float f) {
  union { float f; unsigned u; } v; v.f = f;
  unsigned r = v.u + 0x7FFFu + ((v.u >> 16) & 1u);
  return (unsigned short)(r >> 16);
}
__device__ __forceinline__ float bf2f(unsigned short b) {
  union { float f; unsigned u; } v; v.u = ((unsigned)b) << 16;
  return v.f;
}

__device__ __forceinline__ void async_load16(const void* g, void* l) {
  __builtin_amdgcn_global_load_lds((const __attribute__((address_space(1))) void*)g,
                                   (__attribute__((address_space(3))) void*)l, 16, 0, 0);
}

// ---------------- fp32 -> (bf16 hi, bf16 lo) split conversion (8-wide) -------
__global__ void convx_k(const float* __restrict__ x, unsigned short* __restrict__ hi,
                        unsigned short* __restrict__ lo, int n8) {
  int i = blockIdx.x * blockDim.x + threadIdx.x;
  int stride = gridDim.x * blockDim.x;
  for (; i < n8; i += stride) {
    float4 v0 = ((const float4*)x)[2 * i];
    float4 v1 = ((const float4*)x)[2 * i + 1];
    ushort8 h, l;
    h[0] = f2bf(v0.x); l[0] = f2bf(v0.x - bf2f(h[0]));
    h[1] = f2bf(v0.y); l[1] = f2bf(v0.y - bf2f(h[1]));
    h[2] = f2bf(v0.z); l[2] = f2bf(v0.z - bf2f(h[2]));
    h[3] = f2bf(v0.w); l[3] = f2bf(v0.w - bf2f(h[3]));
    h[4] = f2bf(v1.x); l[4] = f2bf(v1.x - bf2f(h[4]));
    h[5] = f2bf(v1.y); l[5] = f2bf(v1.y - bf2f(h[5]));
    h[6] = f2bf(v1.z); l[6] = f2bf(v1.z - bf2f(h[6]));
    h[7] = f2bf(v1.w); l[7] = f2bf(v1.w - bf2f(h[7]));
    ((ushort8*)hi)[i] = h;
    ((ushort8*)lo)[i] = l;
  }
}

// ---------------- w_eff + b_eff (merged) -------------------------------------
__global__ __launch_bounds__(256) void weff_k(const float* __restrict__ pw2_w,
    const float* __restrict__ pw2_b, const float* __restrict__ lin_w,
    const float* __restrict__ lin_b, float* __restrict__ weff) {
  __shared__ float red[256];
  if (blockIdx.x < 8) {
    int h = blockIdx.x * 64 + (threadIdx.x & 63);
    int og = threadIdx.x >> 6;
    float acc = 0.f;
    for (int o = og * 128; o < og * 128 + 128; ++o) acc += pw2_w[o * H_ + h] * lin_w[o];
    red[threadIdx.x] = acc;
    __syncthreads();
    if (threadIdx.x < 64)
      weff[h] = red[threadIdx.x] + red[threadIdx.x + 64] + red[threadIdx.x + 128] + red[threadIdx.x + 192];
  } else {
    int i = threadIdx.x;
    red[i] = pw2_b[i] * lin_w[i] + pw2_b[i + 256] * lin_w[i + 256];
    __syncthreads();
    for (int s = 128; s > 0; s >>= 1) {
      if (i < s) red[i] += red[i + s];
      __syncthreads();
    }
    if (i == 0) weff[H_] = red[0] + lin_b[0];
  }
}

// ---------------- pw1 GEMM: 2-phase K-step, counted vmcnt, XCD swizzle -------
// (exact R3 structure — best measured variant: 101.0 µs, MfmaUtil 47%)
__global__ __launch_bounds__(256) void gemm_mfma_k(
    const unsigned short* __restrict__ Ahi, const unsigned short* __restrict__ Alo,
    const unsigned short* __restrict__ Whi, const unsigned short* __restrict__ Wlo,
    const float* __restrict__ bias, float* __restrict__ g) {
  __shared__ short Ah[2][128 * 32];
  __shared__ short Al[2][128 * 32];
  __shared__ short Bh[2][128 * 32];
  __shared__ short Bl[2][128 * 32];
  const int tid = threadIdx.x;
  const int bid = blockIdx.x;
  const int xcd = bid & 7, ii = bid >> 3;
  const int m0 = (((xcd << 5) + (ii >> 3))) * 128;  // m-panel 0..255
  const int n0 = (ii & 7) * 64;                     // n-block 0..7
  const int w = tid >> 6, lane = tid & 63;
  const int wr = w >> 1, wc = w & 1;

  f32x4 acc[4][4];  // [mt][gate*2+ntp]
#pragma unroll
  for (int mt = 0; mt < 4; ++mt)
#pragma unroll
    for (int nt = 0; nt < 4; ++nt) acc[mt][nt] = (f32x4){0.f, 0.f, 0.f, 0.f};

  // staging geometry (element offsets into global, k-invariant)
  int offA[2], offB[2], ldsb[2];
#pragma unroll
  for (int j = 0; j < 2; ++j) {
    int L = j * 256 + tid;
    int r = L >> 2;
    int csrc = (L & 3) ^ ((r >> 1) & 3);
    offA[j] = (m0 + r) * 512 + csrc * 8;
    int wrow = (r < 64) ? (n0 + r) : (n0 + 448 + r);
    offB[j] = wrow * 512 + csrc * 8;
    ldsb[j] = __builtin_amdgcn_readfirstlane((j * 256 + w * 64) * 16);
  }

  // fragment byte addresses (k-invariant, per-half)
  const int q = lane >> 4;
  int aAddr[4], bAddr[4];
#pragma unroll
  for (int mt = 0; mt < 4; ++mt) {
    int rA = wr * 64 + mt * 16 + (lane & 15);
    aAddr[mt] = rA * 64 + (q ^ ((rA >> 1) & 3)) * 16;
  }
#pragma unroll
  for (int nt = 0; nt < 4; ++nt) {
    int rB = (nt >> 1) * 64 + wc * 32 + (nt & 1) * 16 + (lane & 15);
    bAddr[nt] = rB * 64 + (q ^ ((rB >> 1) & 3)) * 16;
  }

  // prologue: stage k=0 into half 0 (A-group of 4, then B-group of 4)
#pragma unroll
  for (int j = 0; j < 2; ++j) {
    async_load16(Ahi + offA[j], (char*)Ah[0] + ldsb[j]);
    async_load16(Alo + offA[j], (char*)Al[0] + ldsb[j]);
  }
#pragma unroll
  for (int j = 0; j < 2; ++j) {
    async_load16(Whi + offB[j], (char*)Bh[0] + ldsb[j]);
    async_load16(Wlo + offB[j], (char*)Bl[0] + ldsb[j]);
  }

  short8 ah[4], al[4], bh[4], bl[4];

#pragma unroll 2
  for (int kk = 0; kk < 15; ++kk) {
    const int cur = kk & 1;
    const int nxt = cur ^ 1;
    const int k1 = (kk + 1) * 32;

    // -------- phase A: A-tiles of step kk ready; B-tiles still in flight ----
    __builtin_amdgcn_sched_barrier(0);
    asm volatile("s_waitcnt vmcnt(4)" ::: "memory");
    __builtin_amdgcn_s_barrier();
    __builtin_amdgcn_sched_barrier(0);
#pragma unroll
    for (int mt = 0; mt < 4; ++mt) {
      ah[mt] = *(const short8*)((const char*)Ah[cur] + aAddr[mt]);
      al[mt] = *(const short8*)((const char*)Al[cur] + aAddr[mt]);
    }
#pragma unroll
    for (int j = 0; j < 2; ++j) {
      async_load16(Ahi + offA[j] + k1, (char*)Ah[nxt] + ldsb[j]);
      async_load16(Alo + offA[j] + k1, (char*)Al[nxt] + ldsb[j]);
    }

    // -------- phase B: B-tiles of step kk ready; A_{kk+1} in flight ---------
    __builtin_amdgcn_sched_barrier(0);
    asm volatile("s_waitcnt vmcnt(4)" ::: "memory");
    __builtin_amdgcn_s_barrier();
    __builtin_amdgcn_sched_barrier(0);
#pragma unroll
    for (int nt = 0; nt < 4; ++nt) {
      bh[nt] = *(const short8*)((const char*)Bh[cur] + bAddr[nt]);
      bl[nt] = *(const short8*)((const char*)Bl[cur] + bAddr[nt]);
    }
#pragma unroll
    for (int j = 0; j < 2; ++j) {
      async_load16(Whi + offB[j] + k1, (char*)Bh[nxt] + ldsb[j]);
      async_load16(Wlo + offB[j] + k1, (char*)Bl[nxt] + ldsb[j]);
    }

    __builtin_amdgcn_s_setprio(1);
#pragma unroll
    for (int mt = 0; mt < 4; ++mt)
#pragma unroll
      for (int nt = 0; nt < 4; ++nt) {
        acc[mt][nt] = __builtin_amdgcn_mfma_f32_16x16x32_bf16(ah[mt], bh[nt], acc[mt][nt], 0, 0, 0);
        acc[mt][nt] = __builtin_amdgcn_mfma_f32_16x16x32_bf16(al[mt], bh[nt], acc[mt][nt], 0, 0, 0);
        acc[mt][nt] = __builtin_amdgcn_mfma_f32_16x16x32_bf16(ah[mt], bl[nt], acc[mt][nt], 0, 0, 0);
      }
    __builtin_amdgcn_s_setprio(0);
  }

  // -------- peeled final step kk=15 (cur=1): drain to 0 at the end ----------
  {
    __builtin_amdgcn_sched_barrier(0);
    asm volatile("s_waitcnt vmcnt(4)" ::: "memory");
    __builtin_amdgcn_s_barrier();
    __builtin_amdgcn_sched_barrier(0);
#pragma unroll
    for (int mt = 0; mt < 4; ++mt) {
      ah[mt] = *(const short8*)((const char*)Ah[1] + aAddr[mt]);
      al[mt] = *(const short8*)((const char*)Al[1] + aAddr[mt]);
    }
    __builtin_amdgcn_sched_barrier(0);
    asm volatile("s_waitcnt vmcnt(0)" ::: "memory");
    __builtin_amdgcn_s_barrier();
    __builtin_amdgcn_sched_barrier(0);
#pragma unroll
    for (int nt = 0; nt < 4; ++nt) {
      bh[nt] = *(const short8*)((const char*)Bh[1] + bAddr[nt]);
      bl[nt] = *(const short8*)((const char*)Bl[1] + bAddr[nt]);
    }
    __builtin_amdgcn_s_setprio(1);
#pragma unroll
    for (int mt = 0; mt < 4; ++mt)
#pragma unroll
      for (int nt = 0; nt < 4; ++nt) {
        acc[mt][nt] = __builtin_amdgcn_mfma_f32_16x16x32_bf16(ah[mt], bh[nt], acc[mt][nt], 0, 0, 0);
        acc[mt][nt] = __builtin_amdgcn_mfma_f32_16x16x32_bf16(al[mt], bh[nt], acc[mt][nt], 0, 0, 0);
        acc[mt][nt] = __builtin_amdgcn_mfma_f32_16x16x32_bf16(ah[mt], bl[nt], acc[mt][nt], 0, 0, 0);
      }
    __builtin_amdgcn_s_setprio(0);
  }

  // epilogue: GLU (a and gate live in the SAME lane: acc[mt][ntp] / acc[mt][2+ntp])
  const int col = lane & 15, rq = lane >> 4;
#pragma unroll
  for (int mt = 0; mt < 4; ++mt) {
#pragma unroll
    for (int ntp = 0; ntp < 2; ++ntp) {
      int gcol = n0 + wc * 32 + ntp * 16 + col;
      float ba = bias[gcol];
      float bg = bias[512 + gcol];
#pragma unroll
      for (int r = 0; r < 4; ++r) {
        int m = m0 + wr * 64 + mt * 16 + rq * 4 + r;
        float a = acc[mt][ntp][r] + ba;
        float gt = acc[mt][2 + ntp][r] + bg;
        g[(size_t)m * 512 + gcol] = a / (1.f + expf(-gt));
      }
    }
  }
}

// ---------------- depthwise conv + LN + swish + logit-dot + sigmoid ----------
__global__ __launch_bounds__(512) void conv_ln_k(const float* __restrict__ g,
    const float* __restrict__ dw_w, const float* __restrict__ dw_b,
    const float* __restrict__ ln_g, const float* __restrict__ ln_b,
    const float* __restrict__ weff, const int* __restrict__ x_lens,
    float* __restrict__ aT) {
  __shared__ float wlds[H_ * K_];     // 30 KB
  __shared__ float tbuf[16][512];     // 32 KB
  __shared__ float mvs[16], rss[16];
  const int tid = threadIdx.x;
  const int c = tid;
  const int t0 = blockIdx.x * 64;
  const int b = blockIdx.y;

  for (int i = tid; i < H_ * K_; i += 512) wlds[i] = dw_w[i];
  const int xlen = x_lens[b];
  const float* gb = g + ((size_t)b * T_) * H_ + c;

  float gwin[30];
#pragma unroll
  for (int i = 0; i < 30; ++i) {
    int t = t0 - 14 + i;
    gwin[i] = (t >= 0) ? gb[(size_t)t * H_] : 0.f;
  }
  __syncthreads();
  float wreg[15];
#pragma unroll
  for (int k = 0; k < 15; ++k) wreg[k] = wlds[c * 15 + k];
  const float dwb = dw_b[c], lg = ln_g[c], lb = ln_b[c], we = weff[c];
  const float beff = weff[H_];
  const int tt = tid >> 5, p = tid & 31;

#pragma unroll 1
  for (int qc = 0; qc < 4; ++qc) {
    float h2[16];
#pragma unroll
    for (int j = 0; j < 16; ++j) {
      float s = dwb;
#pragma unroll
      for (int k = 0; k < 15; ++k) s += gwin[j + k] * wreg[k];
      h2[j] = s;
      tbuf[j][c] = s;
    }
    __syncthreads();
    float s1 = 0.f, s2 = 0.f;
#pragma unroll
    for (int k = 0; k < 16; ++k) {
      float v = tbuf[tt][k * 32 + p];
      s1 += v; s2 += v * v;
    }
#pragma unroll
    for (int off = 16; off > 0; off >>= 1) {
      s1 += __shfl_down(s1, off, 32);
      s2 += __shfl_down(s2, off, 32);
    }
    if (p == 0) {
      float m = s1 * (1.f / 512.f);
      float v = s2 * (1.f / 512.f) - m * m;
      mvs[tt] = m;
      rss[tt] = rsqrtf(v + 1e-5f);
    }
    __syncthreads();
#pragma unroll
    for (int j = 0; j < 16; ++j) {
      float y = (h2[j] - mvs[j]) * rss[j] * lg + lb;
      float sw = y / (1.f + expf(-y));
      tbuf[j][c] = sw * we;
    }
    __syncthreads();
    float s = 0.f;
#pragma unroll
    for (int k = 0; k < 16; ++k) s += tbuf[tt][k * 32 + p];
#pragma unroll
    for (int off = 16; off > 0; off >>= 1) s += __shfl_down(s, off, 32);
    if (p == 0) {
      float logit = s + beff;
      float a = 1.f / (1.f + expf(-logit));
      int t = t0 + qc * 16 + tt;
      if (t >= xlen) a = 0.f;
      aT[t * B_ + b] = a;
    }
    if (qc < 3) {
#pragma unroll
      for (int i = 0; i < 14; ++i) gwin[i] = gwin[i + 16];
#pragma unroll
      for (int i = 0; i < 16; ++i)
        gwin[14 + i] = gb[(size_t)(t0 + qc * 16 + 16 + i) * H_];
    }
    __syncthreads();
  }
}

// ---------------- fused CIF: serial fp32 scan (lane 0) + 64-lane replay ------
// One block per batch. Alphas staged in LDS (8KB). Lane 0 reproduces the
// EXACT serial fp32 recurrence (fire decisions must not re-round), writing
// 64 checkpoints to LDS; then all 64 lanes replay their 32-step segment.
__global__ __launch_bounds__(64) void cif_k(const float* __restrict__ aT,
    float* __restrict__ wdT, float* __restrict__ wrT,
    int* __restrict__ fire_pos, int* __restrict__ nfires, float* __restrict__ tok) {
  __shared__ float alds[T_];
  __shared__ float chks[64];
  const int b = blockIdx.x;
  const int seg = threadIdx.x;

  for (int t = seg; t < T_; t += 64) alds[t] = aT[t * B_ + b];
  __syncthreads();

  if (seg == 0) {
    float integ = 0.f;
#pragma unroll 1
    for (int s = 0; s < 64; ++s) {
      chks[s] = integ;
#pragma unroll
      for (int j = 0; j < 32; ++j) {
        float ni = integ + alds[s * 32 + j];
        integ = ni - floorf(ni);
      }
    }
  }
  __syncthreads();

  const int t0 = seg * 32;
  float integ = chks[seg];
  float a[32];
#pragma unroll
  for (int j = 0; j < 32; ++j) a[j] = alds[t0 + j];
  unsigned fmask = 0u;
  float ssum = 0.f;
#pragma unroll
  for (int j = 0; j < 32; ++j) {
    float al = a[j];
    float dist = 1.0f - integ;
    float ni = integ + al;
    bool fire = ni >= 1.0f;
    float cur = fire ? dist : al;
    wdT[(t0 + j) * B_ + b] = cur;
    wrT[(t0 + j) * B_ + b] = al - cur;
    if (fire) fmask |= (1u << j);
    integ = ni - floorf(ni);
    ssum += al;
  }
  const int cnt = __popc(fmask);
  int incl = cnt;
#pragma unroll
  for (int off = 1; off < 64; off <<= 1) {
    int v = __shfl_up(incl, off, 64);
    if (seg >= off) incl += v;
  }
  int idx = incl - cnt;
  unsigned m = fmask;
  while (m) {
    int j = __ffs(m) - 1;
    m &= m - 1;
    fire_pos[b * T_ + idx++] = t0 + j;
  }
  if (seg == 63) nfires[b] = incl;
#pragma unroll
  for (int off = 32; off > 0; off >>= 1) ssum += __shfl_down(ssum, off, 64);
  if (seg == 0) tok[b] = ssum;
}

// ---------------- gather fired frames: 16 rows per block ---------------------
// Consecutive j share the segment boundary (ts(j)=te(j-1), kept in register)
// and the fire_pos cacheline; per-block launch/latency overhead amortized 16x,
// and the chunk's x reads cover one contiguous t-range.
#define JCHUNK 16
__global__ __launch_bounds__(128) void frames_k(const float* __restrict__ x,
    const float* __restrict__ aT, const float* __restrict__ wdT,
    const float* __restrict__ wrT, const int* __restrict__ fire_pos,
    const int* __restrict__ nfires, float* __restrict__ out0, float* __restrict__ out2) {
  const int b = blockIdx.y;
  const int j0 = blockIdx.x * JCHUNK;
  const int h = threadIdx.x << 2;
  const int nf = nfires[b];
  const float* xb = x + ((size_t)b * T_) * H_;
  // ts for the first j of the chunk (garbage harmless if j0 >= nf; in-bounds)
  int ts = (j0 > 0) ? fire_pos[b * T_ + j0 - 1] : -1;

#pragma unroll 1
  for (int j = j0; j < j0 + JCHUNK; ++j) {
    const size_t ob = ((size_t)b * T_ + j) * H_;
    if (j >= nf) {
      float4 z = make_float4(0.f, 0.f, 0.f, 0.f);
      *(float4*)(out0 + ob + h) = z;
      *(float4*)(out2 + ob + h) = z;
      continue;
    }
    const int te = fire_pos[b * T_ + j];
    float4 acc = make_float4(0.f, 0.f, 0.f, 0.f);
    if (j > 0) {
      float wv = wrT[ts * B_ + b];
      float4 xv = *(const float4*)(xb + (size_t)ts * H_ + h);
      acc.x = wv * xv.x; acc.y = wv * xv.y; acc.z = wv * xv.z; acc.w = wv * xv.w;
    }
    for (int t = ts + 1; t < te; ++t) {
      float wv = aT[t * B_ + b];
      float4 xv = *(const float4*)(xb + (size_t)t * H_ + h);
      acc.x += wv * xv.x; acc.y += wv * xv.y; acc.z += wv * xv.z; acc.w += wv * xv.w;
    }
    {
      float wv = wdT[te * B_ + b];
      float4 xv = *(const float4*)(xb + (size_t)te * H_ + h);
      acc.x += wv * xv.x; acc.y += wv * xv.y; acc.z += wv * xv.z; acc.w += wv * xv.w;
    }
    *(float4*)(out0 + ob + h) = acc;
    float4 racc = make_float4(acc.w, acc.z, acc.y, acc.x);
    *(float4*)(out2 + ob + (H_ - 4 - h)) = racc;
    ts = te;
  }
}

extern "C" void kernel_launch(void* const* d_in, const int* in_sizes, int n_in,
                              void* d_out, int out_size, void* d_ws, size_t ws_size,
                              hipStream_t stream) {
  const float* x     = (const float*)d_in[0];
  const int*   xlens = (const int*)d_in[1];
  const float* pw1_w = (const float*)d_in[2];
  const float* pw1_b = (const float*)d_in[3];
  const float* dw_w  = (const float*)d_in[4];
  const float* dw_b  = (const float*)d_in[5];
  const float* ln_g  = (const float*)d_in[6];
  const float* ln_b  = (const float*)d_in[7];
  const float* pw2_w = (const float*)d_in[8];
  const float* pw2_b = (const float*)d_in[9];
  const float* lin_w = (const float*)d_in[10];
  const float* lin_b = (const float*)d_in[11];

  float* out0 = (float*)d_out;                       // fired_frames (B,T,H)
  float* tok  = out0 + (size_t)B_ * T_ * H_;         // predicted_token_nums (B,)
  float* out2 = tok + B_;                            // r_fired_frames (B,T,H)

  char* ws = (char*)d_ws;
  float* g             = (float*)ws;                              // 64 MB
  unsigned short* Ahi  = (unsigned short*)(ws + (size_t)M_ * H_ * 4);
  unsigned short* Alo  = Ahi + (size_t)M_ * H_;
  unsigned short* Whi  = Alo + (size_t)M_ * H_;
  unsigned short* Wlo  = Whi + (size_t)2 * H_ * H_;
  float* aT       = (float*)(Wlo + (size_t)2 * H_ * H_);
  float* wdT      = aT + B_ * T_;
  float* wrT      = wdT + B_ * T_;
  int*   fire_pos = (int*)(wrT + B_ * T_);
  int*   nfires   = fire_pos + B_ * T_;
  float* weff     = (float*)(nfires + 64);

  convx_k<<<2048, 256, 0, stream>>>(x, Ahi, Alo, M_ * H_ / 8);
  convx_k<<<256, 256, 0, stream>>>(pw1_w, Whi, Wlo, 2 * H_ * H_ / 8);
  weff_k<<<9, 256, 0, stream>>>(pw2_w, pw2_b, lin_w, lin_b, weff);
  gemm_mfma_k<<<2048, 256, 0, stream>>>(Ahi, Alo, Whi, Wlo, pw1_b, g);
  conv_ln_k<<<dim3(32, 16), 512, 0, stream>>>(g, dw_w, dw_b, ln_g, ln_b, weff, xlens, aT);
  cif_k<<<16, 64, 0, stream>>>(aT, wdT, wrT, fire_pos, nfires, tok);
  frames_k<<<dim3(T_ / JCHUNK, 16), 128, 0, stream>>>(x, aT, wdT, wrT, fire_pos, nfires, out0, out2);
}

// Round 7
// 435.956 us; speedup vs baseline: 1.0528x; 1.0528x over previous
//
#include <hip/hip_runtime.h>
#include <math.h>

#define B_ 16
#define T_ 2048
#define H_ 512
#define K_ 15
#define M_ (B_*T_)   // 32768

typedef __attribute__((ext_vector_type(8))) short short8;
typedef __attribute__((ext_vector_type(8))) unsigned short ushort8;
typedef __attribute__((ext_vector_type(4))) float f32x4;

__device__ __forceinline__ unsigned short f2bf(float f) {
  union { float f; unsigned u; } v; v.f = f;
  unsigned r = v.u + 0x7FFFu + ((v.u >> 16) & 1u);
  return (unsigned short)(r >> 16);
}
__device__ __forceinline__ float bf2f(unsigned short b) {
  union { float f; unsigned u; } v; v.u = ((unsigned)b) << 16;
  return v.f;
}

__device__ __forceinline__ void async_load16(const void* g, void* l) {
  __builtin_amdgcn_global_load_lds((const __attribute__((address_space(1))) void*)g,
                                   (__attribute__((address_space(3))) void*)l, 16, 0, 0);
}

// ---------------- fp32 -> (bf16 hi, bf16 lo) split conversion (8-wide) -------
__global__ void convx_k(const float* __restrict__ x, unsigned short* __restrict__ hi,
                        unsigned short* __restrict__ lo, int n8) {
  int i = blockIdx.x * blockDim.x + threadIdx.x;
  int stride = gridDim.x * blockDim.x;
  for (; i < n8; i += stride) {
    float4 v0 = ((const float4*)x)[2 * i];
    float4 v1 = ((const float4*)x)[2 * i + 1];
    ushort8 h, l;
    h[0] = f2bf(v0.x); l[0] = f2bf(v0.x - bf2f(h[0]));
    h[1] = f2bf(v0.y); l[1] = f2bf(v0.y - bf2f(h[1]));
    h[2] = f2bf(v0.z); l[2] = f2bf(v0.z - bf2f(h[2]));
    h[3] = f2bf(v0.w); l[3] = f2bf(v0.w - bf2f(h[3]));
    h[4] = f2bf(v1.x); l[4] = f2bf(v1.x - bf2f(h[4]));
    h[5] = f2bf(v1.y); l[5] = f2bf(v1.y - bf2f(h[5]));
    h[6] = f2bf(v1.z); l[6] = f2bf(v1.z - bf2f(h[6]));
    h[7] = f2bf(v1.w); l[7] = f2bf(v1.w - bf2f(h[7]));
    ((ushort8*)hi)[i] = h;
    ((ushort8*)lo)[i] = l;
  }
}

// ---------------- w_eff + b_eff (merged) -------------------------------------
__global__ __launch_bounds__(256) void weff_k(const float* __restrict__ pw2_w,
    const float* __restrict__ pw2_b, const float* __restrict__ lin_w,
    const float* __restrict__ lin_b, float* __restrict__ weff) {
  __shared__ float red[256];
  if (blockIdx.x < 8) {
    int h = blockIdx.x * 64 + (threadIdx.x & 63);
    int og = threadIdx.x >> 6;
    float acc = 0.f;
    for (int o = og * 128; o < og * 128 + 128; ++o) acc += pw2_w[o * H_ + h] * lin_w[o];
    red[threadIdx.x] = acc;
    __syncthreads();
    if (threadIdx.x < 64)
      weff[h] = red[threadIdx.x] + red[threadIdx.x + 64] + red[threadIdx.x + 128] + red[threadIdx.x + 192];
  } else {
    int i = threadIdx.x;
    red[i] = pw2_b[i] * lin_w[i] + pw2_b[i + 256] * lin_w[i + 256];
    __syncthreads();
    for (int s = 128; s > 0; s >>= 1) {
      if (i < s) red[i] += red[i + s];
      __syncthreads();
    }
    if (i == 0) weff[H_] = red[0] + lin_b[0];
  }
}

// ---------------- pw1 GEMM: 2-phase K-step, counted vmcnt, XCD swizzle -------
// (R3/R6 structure — best measured variant: 99.0 µs, MfmaUtil 47%)
__global__ __launch_bounds__(256) void gemm_mfma_k(
    const unsigned short* __restrict__ Ahi, const unsigned short* __restrict__ Alo,
    const unsigned short* __restrict__ Whi, const unsigned short* __restrict__ Wlo,
    const float* __restrict__ bias, float* __restrict__ g) {
  __shared__ short Ah[2][128 * 32];
  __shared__ short Al[2][128 * 32];
  __shared__ short Bh[2][128 * 32];
  __shared__ short Bl[2][128 * 32];
  const int tid = threadIdx.x;
  const int bid = blockIdx.x;
  const int xcd = bid & 7, ii = bid >> 3;
  const int m0 = (((xcd << 5) + (ii >> 3))) * 128;  // m-panel 0..255
  const int n0 = (ii & 7) * 64;                     // n-block 0..7
  const int w = tid >> 6, lane = tid & 63;
  const int wr = w >> 1, wc = w & 1;

  f32x4 acc[4][4];  // [mt][gate*2+ntp]
#pragma unroll
  for (int mt = 0; mt < 4; ++mt)
#pragma unroll
    for (int nt = 0; nt < 4; ++nt) acc[mt][nt] = (f32x4){0.f, 0.f, 0.f, 0.f};

  // staging geometry (element offsets into global, k-invariant)
  int offA[2], offB[2], ldsb[2];
#pragma unroll
  for (int j = 0; j < 2; ++j) {
    int L = j * 256 + tid;
    int r = L >> 2;
    int csrc = (L & 3) ^ ((r >> 1) & 3);
    offA[j] = (m0 + r) * 512 + csrc * 8;
    int wrow = (r < 64) ? (n0 + r) : (n0 + 448 + r);
    offB[j] = wrow * 512 + csrc * 8;
    ldsb[j] = __builtin_amdgcn_readfirstlane((j * 256 + w * 64) * 16);
  }

  // fragment byte addresses (k-invariant, per-half)
  const int q = lane >> 4;
  int aAddr[4], bAddr[4];
#pragma unroll
  for (int mt = 0; mt < 4; ++mt) {
    int rA = wr * 64 + mt * 16 + (lane & 15);
    aAddr[mt] = rA * 64 + (q ^ ((rA >> 1) & 3)) * 16;
  }
#pragma unroll
  for (int nt = 0; nt < 4; ++nt) {
    int rB = (nt >> 1) * 64 + wc * 32 + (nt & 1) * 16 + (lane & 15);
    bAddr[nt] = rB * 64 + (q ^ ((rB >> 1) & 3)) * 16;
  }

  // prologue: stage k=0 into half 0 (A-group of 4, then B-group of 4)
#pragma unroll
  for (int j = 0; j < 2; ++j) {
    async_load16(Ahi + offA[j], (char*)Ah[0] + ldsb[j]);
    async_load16(Alo + offA[j], (char*)Al[0] + ldsb[j]);
  }
#pragma unroll
  for (int j = 0; j < 2; ++j) {
    async_load16(Whi + offB[j], (char*)Bh[0] + ldsb[j]);
    async_load16(Wlo + offB[j], (char*)Bl[0] + ldsb[j]);
  }

  short8 ah[4], al[4], bh[4], bl[4];

#pragma unroll 2
  for (int kk = 0; kk < 15; ++kk) {
    const int cur = kk & 1;
    const int nxt = cur ^ 1;
    const int k1 = (kk + 1) * 32;

    // -------- phase A: A-tiles of step kk ready; B-tiles still in flight ----
    __builtin_amdgcn_sched_barrier(0);
    asm volatile("s_waitcnt vmcnt(4)" ::: "memory");
    __builtin_amdgcn_s_barrier();
    __builtin_amdgcn_sched_barrier(0);
#pragma unroll
    for (int mt = 0; mt < 4; ++mt) {
      ah[mt] = *(const short8*)((const char*)Ah[cur] + aAddr[mt]);
      al[mt] = *(const short8*)((const char*)Al[cur] + aAddr[mt]);
    }
#pragma unroll
    for (int j = 0; j < 2; ++j) {
      async_load16(Ahi + offA[j] + k1, (char*)Ah[nxt] + ldsb[j]);
      async_load16(Alo + offA[j] + k1, (char*)Al[nxt] + ldsb[j]);
    }

    // -------- phase B: B-tiles of step kk ready; A_{kk+1} in flight ---------
    __builtin_amdgcn_sched_barrier(0);
    asm volatile("s_waitcnt vmcnt(4)" ::: "memory");
    __builtin_amdgcn_s_barrier();
    __builtin_amdgcn_sched_barrier(0);
#pragma unroll
    for (int nt = 0; nt < 4; ++nt) {
      bh[nt] = *(const short8*)((const char*)Bh[cur] + bAddr[nt]);
      bl[nt] = *(const short8*)((const char*)Bl[cur] + bAddr[nt]);
    }
#pragma unroll
    for (int j = 0; j < 2; ++j) {
      async_load16(Whi + offB[j] + k1, (char*)Bh[nxt] + ldsb[j]);
      async_load16(Wlo + offB[j] + k1, (char*)Bl[nxt] + ldsb[j]);
    }

    __builtin_amdgcn_s_setprio(1);
#pragma unroll
    for (int mt = 0; mt < 4; ++mt)
#pragma unroll
      for (int nt = 0; nt < 4; ++nt) {
        acc[mt][nt] = __builtin_amdgcn_mfma_f32_16x16x32_bf16(ah[mt], bh[nt], acc[mt][nt], 0, 0, 0);
        acc[mt][nt] = __builtin_amdgcn_mfma_f32_16x16x32_bf16(al[mt], bh[nt], acc[mt][nt], 0, 0, 0);
        acc[mt][nt] = __builtin_amdgcn_mfma_f32_16x16x32_bf16(ah[mt], bl[nt], acc[mt][nt], 0, 0, 0);
      }
    __builtin_amdgcn_s_setprio(0);
  }

  // -------- peeled final step kk=15 (cur=1): drain to 0 at the end ----------
  {
    __builtin_amdgcn_sched_barrier(0);
    asm volatile("s_waitcnt vmcnt(4)" ::: "memory");
    __builtin_amdgcn_s_barrier();
    __builtin_amdgcn_sched_barrier(0);
#pragma unroll
    for (int mt = 0; mt < 4; ++mt) {
      ah[mt] = *(const short8*)((const char*)Ah[1] + aAddr[mt]);
      al[mt] = *(const short8*)((const char*)Al[1] + aAddr[mt]);
    }
    __builtin_amdgcn_sched_barrier(0);
    asm volatile("s_waitcnt vmcnt(0)" ::: "memory");
    __builtin_amdgcn_s_barrier();
    __builtin_amdgcn_sched_barrier(0);
#pragma unroll
    for (int nt = 0; nt < 4; ++nt) {
      bh[nt] = *(const short8*)((const char*)Bh[1] + bAddr[nt]);
      bl[nt] = *(const short8*)((const char*)Bl[1] + bAddr[nt]);
    }
    __builtin_amdgcn_s_setprio(1);
#pragma unroll
    for (int mt = 0; mt < 4; ++mt)
#pragma unroll
      for (int nt = 0; nt < 4; ++nt) {
        acc[mt][nt] = __builtin_amdgcn_mfma_f32_16x16x32_bf16(ah[mt], bh[nt], acc[mt][nt], 0, 0, 0);
        acc[mt][nt] = __builtin_amdgcn_mfma_f32_16x16x32_bf16(al[mt], bh[nt], acc[mt][nt], 0, 0, 0);
        acc[mt][nt] = __builtin_amdgcn_mfma_f32_16x16x32_bf16(ah[mt], bl[nt], acc[mt][nt], 0, 0, 0);
      }
    __builtin_amdgcn_s_setprio(0);
  }

  // epilogue: GLU (a and gate live in the SAME lane: acc[mt][ntp] / acc[mt][2+ntp])
  const int col = lane & 15, rq = lane >> 4;
#pragma unroll
  for (int mt = 0; mt < 4; ++mt) {
#pragma unroll
    for (int ntp = 0; ntp < 2; ++ntp) {
      int gcol = n0 + wc * 32 + ntp * 16 + col;
      float ba = bias[gcol];
      float bg = bias[512 + gcol];
#pragma unroll
      for (int r = 0; r < 4; ++r) {
        int m = m0 + wr * 64 + mt * 16 + rq * 4 + r;
        float a = acc[mt][ntp][r] + ba;
        float gt = acc[mt][2 + ntp][r] + bg;
        g[(size_t)m * 512 + gcol] = a / (1.f + expf(-gt));
      }
    }
  }
}

// ---------------- depthwise conv + LN + swish + logit-dot + sigmoid ----------
__global__ __launch_bounds__(512) void conv_ln_k(const float* __restrict__ g,
    const float* __restrict__ dw_w, const float* __restrict__ dw_b,
    const float* __restrict__ ln_g, const float* __restrict__ ln_b,
    const float* __restrict__ weff, const int* __restrict__ x_lens,
    float* __restrict__ aT) {
  __shared__ float wlds[H_ * K_];     // 30 KB
  __shared__ float tbuf[16][512];     // 32 KB
  __shared__ float mvs[16], rss[16];
  const int tid = threadIdx.x;
  const int c = tid;
  const int t0 = blockIdx.x * 64;
  const int b = blockIdx.y;

  for (int i = tid; i < H_ * K_; i += 512) wlds[i] = dw_w[i];
  const int xlen = x_lens[b];
  const float* gb = g + ((size_t)b * T_) * H_ + c;

  float gwin[30];
#pragma unroll
  for (int i = 0; i < 30; ++i) {
    int t = t0 - 14 + i;
    gwin[i] = (t >= 0) ? gb[(size_t)t * H_] : 0.f;
  }
  __syncthreads();
  float wreg[15];
#pragma unroll
  for (int k = 0; k < 15; ++k) wreg[k] = wlds[c * 15 + k];
  const float dwb = dw_b[c], lg = ln_g[c], lb = ln_b[c], we = weff[c];
  const float beff = weff[H_];
  const int tt = tid >> 5, p = tid & 31;

#pragma unroll 1
  for (int qc = 0; qc < 4; ++qc) {
    float h2[16];
#pragma unroll
    for (int j = 0; j < 16; ++j) {
      float s = dwb;
#pragma unroll
      for (int k = 0; k < 15; ++k) s += gwin[j + k] * wreg[k];
      h2[j] = s;
      tbuf[j][c] = s;
    }
    __syncthreads();
    float s1 = 0.f, s2 = 0.f;
#pragma unroll
    for (int k = 0; k < 16; ++k) {
      float v = tbuf[tt][k * 32 + p];
      s1 += v; s2 += v * v;
    }
#pragma unroll
    for (int off = 16; off > 0; off >>= 1) {
      s1 += __shfl_down(s1, off, 32);
      s2 += __shfl_down(s2, off, 32);
    }
    if (p == 0) {
      float m = s1 * (1.f / 512.f);
      float v = s2 * (1.f / 512.f) - m * m;
      mvs[tt] = m;
      rss[tt] = rsqrtf(v + 1e-5f);
    }
    __syncthreads();
#pragma unroll
    for (int j = 0; j < 16; ++j) {
      float y = (h2[j] - mvs[j]) * rss[j] * lg + lb;
      float sw = y / (1.f + expf(-y));
      tbuf[j][c] = sw * we;
    }
    __syncthreads();
    float s = 0.f;
#pragma unroll
    for (int k = 0; k < 16; ++k) s += tbuf[tt][k * 32 + p];
#pragma unroll
    for (int off = 16; off > 0; off >>= 1) s += __shfl_down(s, off, 32);
    if (p == 0) {
      float logit = s + beff;
      float a = 1.f / (1.f + expf(-logit));
      int t = t0 + qc * 16 + tt;
      if (t >= xlen) a = 0.f;
      aT[t * B_ + b] = a;
    }
    if (qc < 3) {
#pragma unroll
      for (int i = 0; i < 14; ++i) gwin[i] = gwin[i + 16];
#pragma unroll
      for (int i = 0; i < 16; ++i)
        gwin[14 + i] = gb[(size_t)(t0 + qc * 16 + 16 + i) * H_];
    }
    __syncthreads();
  }
}

// ---------------- fused CIF: serial fp32 scan (lane 0) + 64-lane replay ------
__global__ __launch_bounds__(64) void cif_k(const float* __restrict__ aT,
    float* __restrict__ wdT, float* __restrict__ wrT,
    int* __restrict__ fire_pos, int* __restrict__ nfires, float* __restrict__ tok) {
  __shared__ float alds[T_];
  __shared__ float chks[64];
  const int b = blockIdx.x;
  const int seg = threadIdx.x;

  for (int t = seg; t < T_; t += 64) alds[t] = aT[t * B_ + b];
  __syncthreads();

  if (seg == 0) {
    float integ = 0.f;
#pragma unroll 1
    for (int s = 0; s < 64; ++s) {
      chks[s] = integ;
#pragma unroll
      for (int j = 0; j < 32; ++j) {
        float ni = integ + alds[s * 32 + j];
        integ = ni - floorf(ni);
      }
    }
  }
  __syncthreads();

  const int t0 = seg * 32;
  float integ = chks[seg];
  float a[32];
#pragma unroll
  for (int j = 0; j < 32; ++j) a[j] = alds[t0 + j];
  unsigned fmask = 0u;
  float ssum = 0.f;
#pragma unroll
  for (int j = 0; j < 32; ++j) {
    float al = a[j];
    float dist = 1.0f - integ;
    float ni = integ + al;
    bool fire = ni >= 1.0f;
    float cur = fire ? dist : al;
    wdT[(t0 + j) * B_ + b] = cur;
    wrT[(t0 + j) * B_ + b] = al - cur;
    if (fire) fmask |= (1u << j);
    integ = ni - floorf(ni);
    ssum += al;
  }
  const int cnt = __popc(fmask);
  int incl = cnt;
#pragma unroll
  for (int off = 1; off < 64; off <<= 1) {
    int v = __shfl_up(incl, off, 64);
    if (seg >= off) incl += v;
  }
  int idx = incl - cnt;
  unsigned m = fmask;
  while (m) {
    int j = __ffs(m) - 1;
    m &= m - 1;
    fire_pos[b * T_ + idx++] = t0 + j;
  }
  if (seg == 63) nfires[b] = incl;
#pragma unroll
  for (int off = 32; off > 0; off >>= 1) ssum += __shfl_down(ssum, off, 64);
  if (seg == 0) tok[b] = ssum;
}

// ---------------- gather fired frames + reversed copy + zero-fill tail -------
// One block per output row (massive TLP hides the fire_pos/weight latency
// chains — measured better than 16-row chunking, R6 post-mortem).
__global__ __launch_bounds__(128) void frames_k(const float* __restrict__ x,
    const float* __restrict__ aT, const float* __restrict__ wdT,
    const float* __restrict__ wrT, const int* __restrict__ fire_pos,
    const int* __restrict__ nfires, float* __restrict__ out0, float* __restrict__ out2) {
  const int b = blockIdx.y;
  const int j = blockIdx.x;
  const int h = threadIdx.x << 2;
  const size_t ob = ((size_t)b * T_ + j) * H_;
  if (j >= nfires[b]) {
    float4 z = make_float4(0.f, 0.f, 0.f, 0.f);
    *(float4*)(out0 + ob + h) = z;
    *(float4*)(out2 + ob + h) = z;
    return;
  }
  const int te = fire_pos[b * T_ + j];
  const int ts = (j > 0) ? fire_pos[b * T_ + j - 1] : -1;
  const float* xb = x + ((size_t)b * T_) * H_;
  float4 acc = make_float4(0.f, 0.f, 0.f, 0.f);
  if (j > 0) {
    float w = wrT[ts * B_ + b];
    float4 xv = *(const float4*)(xb + (size_t)ts * H_ + h);
    acc.x = w * xv.x; acc.y = w * xv.y; acc.z = w * xv.z; acc.w = w * xv.w;
  }
  for (int t = ts + 1; t < te; ++t) {
    float w = aT[t * B_ + b];
    float4 xv = *(const float4*)(xb + (size_t)t * H_ + h);
    acc.x += w * xv.x; acc.y += w * xv.y; acc.z += w * xv.z; acc.w += w * xv.w;
  }
  {
    float w = wdT[te * B_ + b];
    float4 xv = *(const float4*)(xb + (size_t)te * H_ + h);
    acc.x += w * xv.x; acc.y += w * xv.y; acc.z += w * xv.z; acc.w += w * xv.w;
  }
  *(float4*)(out0 + ob + h) = acc;
  float4 racc = make_float4(acc.w, acc.z, acc.y, acc.x);
  *(float4*)(out2 + ob + (H_ - 4 - h)) = racc;
}

extern "C" void kernel_launch(void* const* d_in, const int* in_sizes, int n_in,
                              void* d_out, int out_size, void* d_ws, size_t ws_size,
                              hipStream_t stream) {
  const float* x     = (const float*)d_in[0];
  const int*   xlens = (const int*)d_in[1];
  const float* pw1_w = (const float*)d_in[2];
  const float* pw1_b = (const float*)d_in[3];
  const float* dw_w  = (const float*)d_in[4];
  const float* dw_b  = (const float*)d_in[5];
  const float* ln_g  = (const float*)d_in[6];
  const float* ln_b  = (const float*)d_in[7];
  const float* pw2_w = (const float*)d_in[8];
  const float* pw2_b = (const float*)d_in[9];
  const float* lin_w = (const float*)d_in[10];
  const float* lin_b = (const float*)d_in[11];

  float* out0 = (float*)d_out;                       // fired_frames (B,T,H)
  float* tok  = out0 + (size_t)B_ * T_ * H_;         // predicted_token_nums (B,)
  float* out2 = tok + B_;                            // r_fired_frames (B,T,H)

  char* ws = (char*)d_ws;
  float* g             = (float*)ws;                              // 64 MB
  unsigned short* Ahi  = (unsigned short*)(ws + (size_t)M_ * H_ * 4);
  unsigned short* Alo  = Ahi + (size_t)M_ * H_;
  unsigned short* Whi  = Alo + (size_t)M_ * H_;
  unsigned short* Wlo  = Whi + (size_t)2 * H_ * H_;
  float* aT       = (float*)(Wlo + (size_t)2 * H_ * H_);
  float* wdT      = aT + B_ * T_;
  float* wrT      = wdT + B_ * T_;
  int*   fire_pos = (int*)(wrT + B_ * T_);
  int*   nfires   = fire_pos + B_ * T_;
  float* weff     = (float*)(nfires + 64);

  convx_k<<<2048, 256, 0, stream>>>(x, Ahi, Alo, M_ * H_ / 8);
  convx_k<<<256, 256, 0, stream>>>(pw1_w, Whi, Wlo, 2 * H_ * H_ / 8);
  weff_k<<<9, 256, 0, stream>>>(pw2_w, pw2_b, lin_w, lin_b, weff);
  gemm_mfma_k<<<2048, 256, 0, stream>>>(Ahi, Alo, Whi, Wlo, pw1_b, g);
  conv_ln_k<<<dim3(32, 16), 512, 0, stream>>>(g, dw_w, dw_b, ln_g, ln_b, weff, xlens, aT);
  cif_k<<<16, 64, 0, stream>>>(aT, wdT, wrT, fire_pos, nfires, tok);
  frames_k<<<dim3(2048, 16), 128, 0, stream>>>(x, aT, wdT, wrT, fire_pos, nfires, out0, out2);
}